// Round 9
// baseline (231.226 us; speedup 1.0000x reference)
//
#include <hip/hip_runtime.h>
#include <hip/hip_bf16.h>
#include <math.h>
#include <stdint.h>

typedef __hip_bfloat16 hbf16;

#define T_TOK 2048
#define H_DIM 1024
#define E_NUM 32
#define I_DIM 256
#define O_DIM 512
#define CAP   2048
#define TT    16
#define WT    16
#define XSTR2 520    // xA/zA half-K row stride in ushorts (512 + 8 pad; 16B-aligned)
#define HSTR  264    // hsm row stride in ushorts (256 + 8 pad)
// r7 post-mortem: counts[32] = ONE 128B cache line; 8192 same-line atomics
// serialized in L2 (~17cy each = the invariant ~60us router wall, r4-r6).
// Pad each expert counter to its own cache line: 32-way parallel streams.
// (r8: validated — total 241 -> 210us, router left the top-5.)
#define CSTR  32     // counts stride in ints (128 B)

typedef __bf16 bf16x8 __attribute__((ext_vector_type(8)));
typedef float  f32x4  __attribute__((ext_vector_type(4)));

__device__ __forceinline__ float b2f(hbf16 v) { return __bfloat162float(v); }
__device__ __forceinline__ float bb2f(ushort u) { return __uint_as_float((uint32_t)u << 16); }

__device__ __forceinline__ ushort f2b(float f) {   // fp32->bf16 RNE
    uint32_t u = __float_as_uint(f);
    return (ushort)((u + 0x7FFFu + ((u >> 16) & 1u)) >> 16);
}

template<int BF>
__device__ __forceinline__ float ld(const void* p, size_t i) {
    if (BF) return b2f(((const hbf16*)p)[i]);
    else    return ((const float*)p)[i];
}

__device__ __forceinline__ f32x4 mfma_bf16(bf16x8 a, bf16x8 b, f32x4 c) {
    return __builtin_amdgcn_mfma_f32_16x16x32_bf16(a, b, c, 0, 0, 0);
}

// Pin prefetch loads before the MFMA region so the register allocator must
// keep the double buffer live (r3: compiler sank loads, VGPR 68, serial chain).
__device__ __forceinline__ void sched_fence() { __builtin_amdgcn_sched_barrier(0); }

// ---------------------------------------------------------------------------
// detect: dtype flag + zero counts (counts needed before router)
// ---------------------------------------------------------------------------
__global__ __launch_bounds__(256) void detect_kernel(
    const uint32_t* __restrict__ xw, int* __restrict__ flag, int* __restrict__ counts)
{
    __shared__ int cnt;
    if (threadIdx.x == 0) cnt = 0;
    if (threadIdx.x < E_NUM) counts[threadIdx.x * CSTR] = 0;
    __syncthreads();
    int c = 0;
    for (int i = threadIdx.x; i < 1024; i += 256) {
        int e = (xw[i] >> 7) & 0xFF;
        if (e >= 110 && e <= 140) c++;
    }
    atomicAdd(&cnt, c);
    __syncthreads();
    if (threadIdx.x == 0) *flag = (cnt > 512) ? 1 : 0;
}

// ===========================================================================
// FAST PATH (ws_size >= 58 MB)
// ===========================================================================

// ---- fused transpose+convert, 32(K) x 128(N) tiles, vectorized ----
// OUTPUT LAYOUT (fragment-blocked): element (n, k) of an E-slice goes to
//   dst[e*K*N + ((k>>5)*N + n)*32 + (k&31)]
__device__ void conv3_tile(const void* __restrict__ src, ushort* __restrict__ dst,
                           int bf, int K, int N, int b, float* __restrict__ sh)
{
    int tilesN = N >> 7, tilesK = K >> 5;
    int e  = b / (tilesK * tilesN);
    int r  = b % (tilesK * tilesN);
    int k0 = (r / tilesN) << 5;
    int n0 = (r % tilesN) << 7;
    size_t base = (size_t)e * K * N;
    int tid = threadIdx.x;
    {
        int row = tid >> 3, c0 = (tid & 7) * 16;
        if (!bf) {
            const float* sp = (const float*)src + base + (size_t)(k0 + row) * N + n0 + c0;
            #pragma unroll
            for (int i = 0; i < 4; ++i) {
                float4 v = *(const float4*)(sp + i * 4);
                sh[row * 132 + c0 + i*4 + 0] = v.x;
                sh[row * 132 + c0 + i*4 + 1] = v.y;
                sh[row * 132 + c0 + i*4 + 2] = v.z;
                sh[row * 132 + c0 + i*4 + 3] = v.w;
            }
        } else {
            const hbf16* sp = (const hbf16*)src + base + (size_t)(k0 + row) * N + n0 + c0;
            #pragma unroll
            for (int i = 0; i < 16; ++i) sh[row * 132 + c0 + i] = b2f(sp[i]);
        }
    }
    __syncthreads();
    {
        int nn = tid >> 1, kk = (tid & 1) * 16;
        union { ushort v[16]; uint4 u[2]; } R;
        #pragma unroll
        for (int i = 0; i < 16; ++i) R.v[i] = f2b(sh[(kk + i) * 132 + nn]);
        // blocked: ((k0>>5)*N + n)*32 + (kk..kk+15)
        ushort* dp = dst + base + ((size_t)(k0 >> 5) * N + (n0 + nn)) * 32 + kk;
        *(uint4*)dp       = R.u[0];
        *(uint4*)(dp + 8) = R.u[1];
    }
    __syncthreads();
}

// ---------------------------------------------------------------------------
// router body (r6 structure): 2 tokens, 256 thr. x staged once, K split
// 8-ways (thread=(half,e)), Wr direct from global, LDS reduce, tail.
// Runs as blocks 0..1023 of the fused kernel, overlapped with convert.
// ---------------------------------------------------------------------------
template<int BF>
__device__ void router3_body(const void* __restrict__ x, const void* __restrict__ Wr,
                             void* __restrict__ out_base,
                             int* __restrict__ counts, int* __restrict__ tok_list,
                             float* __restrict__ wt_list,
                             float* __restrict__ xs, float* __restrict__ sl,
                             float* __restrict__ sf, int t0)
{
    int tid  = threadIdx.x;
    int e    = tid & 31;
    int half = tid >> 5;          // 0..7 (K chunk)

    // ---- stage x[2][1024] -> fp32 LDS (128 thr/row, 8 floats each) ----
    {
        int t = tid >> 7;           // 0..1
        int c = (tid & 127) * 8;
        if (!BF) {
            const float* xp = (const float*)x + (size_t)(t0 + t) * H_DIM + c;
            *(float4*)&xs[t*1024 + c]     = *(const float4*)xp;
            *(float4*)&xs[t*1024 + c + 4] = *(const float4*)(xp + 4);
        } else {
            const hbf16* xp = (const hbf16*)x + (size_t)(t0 + t) * H_DIM + c;
            #pragma unroll
            for (int j = 0; j < 8; ++j) xs[t*1024 + c + j] = b2f(xp[j]);
        }
    }
    __syncthreads();

    // ---- 128-k partial dot for both tokens; Wr direct from global ----
    float a0 = 0.f, a1 = 0.f;
    int kbase = half * 128;
    const float* xr0 = &xs[kbase];
    const float* xr1 = &xs[1024 + kbase];
    #pragma unroll 8
    for (int k = 0; k < 128; ++k) {
        float w = ld<BF>(Wr, (size_t)(kbase + k) * E_NUM + e);
        a0 = fmaf(xr0[k], w, a0);
        a1 = fmaf(xr1[k], w, a1);
    }
    sl[(0*8 + half)*32 + e] = a0;
    sl[(1*8 + half)*32 + e] = a1;
    __syncthreads();

    // ---- reduce 8 partials, write logits ----
    if (tid < 64) {
        int t  = tid >> 5;
        int ee = tid & 31;
        float s = 0.f;
        #pragma unroll
        for (int h = 0; h < 8; ++h) s += sl[(t*8 + h)*32 + ee];
        sf[t*32 + ee] = s;
        size_t li = (size_t)T_TOK * H_DIM + (size_t)(t0 + t) * E_NUM + ee;
        if (BF) ((hbf16*)out_base)[li] = __float2bfloat16(s);
        else    ((float*)out_base)[li] = s;
    }
    __syncthreads();

    // ---- selection tail (1 thread per token) ----
    if (tid < 2) {
        int t = t0 + tid;
        float s[E_NUM];
        #pragma unroll
        for (int i = 0; i < E_NUM; ++i) s[i] = sf[tid * 32 + i];

        int   selE[4];
        float selL[4];
        int ns = 0;
        for (int g = 0; g < 2; ++g) {
            float sum0 = 0.f, sum1 = 0.f;
            #pragma unroll
            for (int j = 0; j < 8; ++j) {
                sum0 += s[(2*g)   * 8 + j];
                sum1 += s[(2*g+1) * 8 + j];
            }
            int bestSh = (sum1 > sum0) ? (2*g+1) : (2*g);
            int base = bestSh * 8;
            int i1 = 0;
            for (int j = 1; j < 8; ++j) if (s[base+j] > s[base+i1]) i1 = j;
            int i2 = -1;
            for (int j = 0; j < 8; ++j) {
                if (j == i1) continue;
                if (i2 < 0 || s[base+j] > s[base+i2]) i2 = j;
            }
            selE[ns] = base + i1; selL[ns] = s[base+i1]; ++ns;
            selE[ns] = base + i2; selL[ns] = s[base+i2]; ++ns;
        }
        float m = fmaxf(fmaxf(selL[0], selL[1]), fmaxf(selL[2], selL[3]));
        float w[4];
        float sum = 0.f;
        for (int j = 0; j < 4; ++j) { w[j] = expf(selL[j] - m); sum += w[j]; }
        float inv = 1.f / sum;
        for (int j = 0; j < 4; ++j) {
            int ee = selE[j];
            int pos = atomicAdd(&counts[ee * CSTR], 1);   // padded: own cache line
            if (pos >= 0 && pos < CAP) {
                tok_list[ee * CAP + pos] = t | (j << 11);   // pack slot
                wt_list[ee * CAP + pos]  = w[j] * inv;
            }
        }
    }
}

// ---------------------------------------------------------------------------
// FUSED convert + router: 6400 blocks x 256 thr. Blocks 0..1023 = router
// (latency-bound long pole, starts at t=0); blocks 1024..6399 = weight
// convert tiles (BW-bound, fills the machine underneath).
// ---------------------------------------------------------------------------
__global__ __launch_bounds__(256) void fused_cr_kernel(
    const void* x, const void* Wr,
    const void* Wg, const void* Wu, const void* Wd, const void* Wc,
    ushort* Wg_t, ushort* Wu_t, ushort* Wd_t, ushort* Wc_t,
    void* out_base, const int* __restrict__ flag,
    int* counts, int* tok_list, float* wt_list)
{
    __shared__ __align__(16) float sh[32 * 132];   // 16896 B, both paths
    int b = blockIdx.x;
    if (b < 1024) {
        float* xs = sh;             // 2048 floats
        float* sl = sh + 2048;      // 512 floats
        float* sf = sh + 2560;      // 64 floats   (2624 < 4224 total)
        if (*flag) router3_body<1>(x, Wr, out_base, counts, tok_list, wt_list,
                                   xs, sl, sf, b * 2);
        else       router3_body<0>(x, Wr, out_base, counts, tok_list, wt_list,
                                   xs, sl, sf, b * 2);
    } else {
        int bb = b - 1024;
        int bf = *flag;
        if      (bb < 2048) conv3_tile(Wg, Wg_t, bf, 1024,  256, bb,        sh);
        else if (bb < 4096) conv3_tile(Wu, Wu_t, bf, 1024,  256, bb - 2048, sh);
        else if (bb < 5120) conv3_tile(Wd, Wd_t, bf,  256,  512, bb - 4096, sh);
        else                conv3_tile(Wc, Wc_t, bf, 1024, 1024, bb - 5120, sh);
    }
}

// ---------------------------------------------------------------------------
// expert3 (M=16): 512 thr (8 waves), 16 tokens/block, grid (32, 128).
// r8 post-mortem: only ~256 active blocks at M=32 => 1 block/CU, the per-
// block serial load chain (8 prefetch rounds + staging barriers) fully
// exposed (MfmaUtil 8%, occ 12%). Halve M => 512 active blocks = 2/CU so
// two load chains interleave. Same verified m=0 fragment path; A1/m=1
// row-group deleted. LDS 25KB.
// ---------------------------------------------------------------------------
template<int BF>
__device__ void expert3_body(const void* __restrict__ x,
    const ushort* __restrict__ Wg_t, const ushort* __restrict__ Wu_t,
    const ushort* __restrict__ Wd_t,
    const int* __restrict__ counts, const int* __restrict__ tok_list,
    const float* __restrict__ wt_list, ushort* __restrict__ ybuf,
    ushort* __restrict__ xA, ushort* __restrict__ hsm,
    int* __restrict__ tokid, float* __restrict__ twt, int* __restrict__ tslot)
{
    int e = blockIdx.x;
    int n = counts[e * CSTR]; n = n < 0 ? 0 : (n > CAP ? CAP : n);
    int t0 = blockIdx.y * 16;
    if (t0 >= n) return;
    int tid  = threadIdx.x;
    int lane = tid & 63, wv = tid >> 6;        // wv 0..7
    int q = lane >> 4, l15 = lane & 15;

    if (tid < 16) {
        int it = t0 + tid;
        int id; float ww;
        if (it < n) { id = tok_list[e*CAP + it]; ww = wt_list[e*CAP + it]; }
        else        { id = tok_list[e*CAP + t0]; ww = 0.f; }
        tokid[tid] = id & 2047;
        tslot[tid] = (id >> 11) & 3;
        twt[tid]   = ww;
    }
    __syncthreads();

    // blocked-layout frag base: (col)*32 + q*8 ; frag(idx,j) at +idx*8192 + j*512
    const ushort* Bg0 = Wg_t + (size_t)e * (H_DIM * I_DIM) + (wv*32 + l15) * 32 + q*8;
    const ushort* Bu0 = Wu_t + (size_t)e * (H_DIM * I_DIM) + (wv*32 + l15) * 32 + q*8;

    f32x4 Cg[2], Cu[2];
    Cg[0] = (f32x4)0.f; Cg[1] = (f32x4)0.f;
    Cu[0] = (f32x4)0.f; Cu[1] = (f32x4)0.f;

    bf16x8 bg[2][4][2], bu[2][4][2];
    #pragma unroll
    for (int ig = 0; ig < 4; ++ig)
        #pragma unroll
        for (int j = 0; j < 2; ++j) {
            bg[0][ig][j] = *(const bf16x8*)(Bg0 + (size_t)ig*8192 + j*512);
            bu[0][ig][j] = *(const bf16x8*)(Bu0 + (size_t)ig*8192 + j*512);
        }
    sched_fence();   // pin initial preload issue here

    // ---- gate/up over two K-halves; xA restaged per half ----
    #pragma unroll
    for (int hk = 0; hk < 2; ++hk) {
        if (hk) __syncthreads();   // all waves done reading half-0 xA

        // stage x[16][hk*512 .. hk*512+512) -> bf16 LDS (32 thr/row)
        {
            int row = tid >> 5;          // 0..15
            int kb  = (tid & 31) * 8;
            size_t srow = (size_t)tokid[row] * H_DIM + hk * 512;
            #pragma unroll
            for (int c = 0; c < 2; ++c) {
                int k = kb + c * 256;
                union { ushort v[8]; uint4 u; } U;
                if (BF) {
                    U.u = *(const uint4*)((const ushort*)x + srow + k);
                } else {
                    const float* xp = (const float*)x + srow + k;
                    float4 a = *(const float4*)xp;
                    float4 b = *(const float4*)(xp + 4);
                    U.v[0]=f2b(a.x); U.v[1]=f2b(a.y); U.v[2]=f2b(a.z); U.v[3]=f2b(a.w);
                    U.v[4]=f2b(b.x); U.v[5]=f2b(b.y); U.v[6]=f2b(b.z); U.v[7]=f2b(b.w);
                }
                *(uint4*)&xA[row * XSTR2 + k] = U.u;
            }
        }
        __syncthreads();

        #pragma unroll
        for (int g2 = 0; g2 < 4; ++g2) {
            int grp = hk * 4 + g2;
            int cb  = grp & 1;
            if (grp < 7) {
                #pragma unroll
                for (int ig = 0; ig < 4; ++ig)
                    #pragma unroll
                    for (int j = 0; j < 2; ++j) {
                        int idx = (grp + 1) * 4 + ig;
                        bg[cb^1][ig][j] = *(const bf16x8*)(Bg0 + (size_t)idx*8192 + j*512);
                        bu[cb^1][ig][j] = *(const bf16x8*)(Bu0 + (size_t)idx*8192 + j*512);
                    }
            }
            sched_fence();   // prefetch for grp+1 must be ISSUED before these MFMAs
            #pragma unroll
            for (int ig = 0; ig < 4; ++ig) {
                int kl = (g2 * 4 + ig) * 32;     // local K offset within half
                bf16x8 A0 = *(const bf16x8*)&xA[l15 * XSTR2 + kl + q*8];
                #pragma unroll
                for (int j = 0; j < 2; ++j) {
                    Cg[j] = mfma_bf16(A0, bg[cb][ig][j], Cg[j]);
                    Cu[j] = mfma_bf16(A0, bu[cb][ig][j], Cu[j]);
                }
            }
        }
    }

    // ---- down B preload (independent of hsm) issued BEFORE the silu/store ----
    const ushort* Bd0 = Wd_t + (size_t)e * (I_DIM * O_DIM) + (wv*64 + l15) * 32 + q*8;
    bf16x8 bd[2][4][4];
    #pragma unroll
    for (int g2 = 0; g2 < 2; ++g2)
        #pragma unroll
        for (int kc2 = 0; kc2 < 4; ++kc2)
            #pragma unroll
            for (int j = 0; j < 4; ++j)
                bd[g2][kc2][j] = *(const bf16x8*)(Bd0 + (size_t)(g2*4 + kc2)*16384 + j*512);
    sched_fence();   // keep the 32-frag preload in flight across silu + barrier

    // ---- h = silu(g)*u -> hsm (rows 0..15) ----
    #pragma unroll
    for (int j = 0; j < 2; ++j)
        #pragma unroll
        for (int r = 0; r < 4; ++r) {
            float g = Cg[j][r], u = Cu[j][r];
            float h = (g / (1.f + expf(-g))) * u;
            hsm[(q*4 + r) * HSTR + wv*32 + j*16 + l15] = f2b(h);
        }
    __syncthreads();

    // ---- down: K=256 = 8 kc ----
    f32x4 Cd[4];
    #pragma unroll
    for (int j = 0; j < 4; ++j) Cd[j] = (f32x4)0.f;

    #pragma unroll
    for (int g2 = 0; g2 < 2; ++g2)
        #pragma unroll
        for (int kc2 = 0; kc2 < 4; ++kc2) {
            int kc = g2 * 4 + kc2;
            bf16x8 A0 = *(const bf16x8*)&hsm[l15 * HSTR + kc*32 + q*8];
            #pragma unroll
            for (int j = 0; j < 4; ++j)
                Cd[j] = mfma_bf16(A0, bd[g2][kc2][j], Cd[j]);
        }

    // ---- store y = w * down to ybuf[t][slot][col], bf16, guarded ----
    #pragma unroll
    for (int r = 0; r < 4; ++r) {
        int row = q*4 + r;
        if (t0 + row < n) {
            float ww = twt[row];
            size_t base = ((size_t)tokid[row] * 4 + tslot[row]) * O_DIM;
            #pragma unroll
            for (int j = 0; j < 4; ++j)
                ybuf[base + wv*64 + j*16 + l15] = f2b(ww * Cd[j][r]);
        }
    }
}

__global__ __launch_bounds__(512, 2) void expert3_kernel(
    const void* x, const ushort* Wg_t, const ushort* Wu_t, const ushort* Wd_t,
    const int* flag, const int* counts, const int* tok_list, const float* wt_list,
    ushort* ybuf)
{
    __shared__ ushort xA[16 * XSTR2];
    __shared__ ushort hsm[16 * HSTR];
    __shared__ int    tokid[16];
    __shared__ float  twt[16];
    __shared__ int    tslot[16];
    if (*flag) expert3_body<1>(x, Wg_t, Wu_t, Wd_t, counts, tok_list, wt_list,
                               ybuf, xA, hsm, tokid, twt, tslot);
    else       expert3_body<0>(x, Wg_t, Wu_t, Wd_t, counts, tok_list, wt_list,
                               ybuf, xA, hsm, tokid, twt, tslot);
}

// ---------------------------------------------------------------------------
// wc3 (M=16): out = z @ Wc with z rows built from ybuf slot sums. 512 thr,
// 16 rows/block, N=256, grid (128, 4) = 512 active blocks (2/CU). Same
// de-serialization as expert3.
// ---------------------------------------------------------------------------
template<int BF>
__device__ void wc3_body(const ushort* __restrict__ ybuf, const ushort* __restrict__ Wc_t,
                         void* __restrict__ out_base, ushort* __restrict__ zA)
{
    int m0  = blockIdx.x * 16;
    int n0  = blockIdx.y * 256;
    int tid = threadIdx.x;
    int lane = tid & 63, wv = tid >> 6;
    int q = lane >> 4, l15 = lane & 15;

    // blocked: frag(idx,j) at Bc0 + idx*32768 + j*512
    const ushort* Bc0 = Wc_t + (size_t)(n0 + wv*32 + l15) * 32 + q*8;
    f32x4 C[2];
    C[0] = (f32x4)0.f; C[1] = (f32x4)0.f;

    bf16x8 bc[2][4][2];
    #pragma unroll
    for (int ig = 0; ig < 4; ++ig)
        #pragma unroll
        for (int j = 0; j < 2; ++j)
            bc[0][ig][j] = *(const bf16x8*)(Bc0 + (size_t)ig*32768 + j*512);
    sched_fence();

    #pragma unroll
    for (int hk = 0; hk < 2; ++hk) {
        if (hk) __syncthreads();   // all waves done reading half-0 zA

        // ---- stage z[16][half] = slot-pair sums, bf16 (32 thr/row) ----
        {
            int row = tid >> 5;          // 0..15
            int kb  = (tid & 31) * 8;
            int t = m0 + row;
            int s0 = hk ? 2 : 0;
            #pragma unroll
            for (int c = 0; c < 2; ++c) {
                int hl = kb + c * 256;
                const ushort* p0 = ybuf + ((size_t)t * 4 + s0) * O_DIM + hl;
                union { ushort v[8]; uint4 u; } A, B, R;
                A.u = *(const uint4*)p0;
                B.u = *(const uint4*)(p0 + O_DIM);
                #pragma unroll
                for (int i = 0; i < 8; ++i) R.v[i] = f2b(bb2f(A.v[i]) + bb2f(B.v[i]));
                *(uint4*)&zA[row * XSTR2 + hl] = R.u;
            }
        }
        __syncthreads();

        #pragma unroll
        for (int g2 = 0; g2 < 4; ++g2) {
            int grp = hk * 4 + g2;
            int cb  = grp & 1;
            if (grp < 7) {
                #pragma unroll
                for (int ig = 0; ig < 4; ++ig)
                    #pragma unroll
                    for (int j = 0; j < 2; ++j) {
                        int idx = (grp + 1) * 4 + ig;
                        bc[cb^1][ig][j] = *(const bf16x8*)(Bc0 + (size_t)idx*32768 + j*512);
                    }
            }
            sched_fence();   // prefetch issued before MFMAs
            #pragma unroll
            for (int ig = 0; ig < 4; ++ig) {
                int kl = (g2 * 4 + ig) * 32;
                bf16x8 A0 = *(const bf16x8*)&zA[l15 * XSTR2 + kl + q*8];
                #pragma unroll
                for (int j = 0; j < 2; ++j)
                    C[j] = mfma_bf16(A0, bc[cb][ig][j], C[j]);
            }
        }
    }

    #pragma unroll
    for (int j = 0; j < 2; ++j)
        #pragma unroll
        for (int r = 0; r < 4; ++r) {
            int row = m0 + q*4 + r;
            int col = n0 + wv*32 + j*16 + l15;
            size_t o = (size_t)row * H_DIM + col;
            if (BF) ((hbf16*)out_base)[o] = __float2bfloat16(C[j][r]);
            else    ((float*)out_base)[o] = C[j][r];
        }
}

__global__ __launch_bounds__(512, 2) void wc3_kernel(
    const ushort* ybuf, const ushort* Wc_t, void* out_base, const int* flag)
{
    __shared__ ushort zA[16 * XSTR2];
    if (*flag) wc3_body<1>(ybuf, Wc_t, out_base, zA);
    else       wc3_body<0>(ybuf, Wc_t, out_base, zA);
}

// ===========================================================================
// FALLBACK PATH (round-4, known passing) — only if ws is small
// ===========================================================================

__global__ __launch_bounds__(256) void zero_kernel(
    float* __restrict__ z_fp32, float* __restrict__ z_bf16,
    const int* __restrict__ flag, int* __restrict__ counts)
{
    float* base = (*flag) ? z_bf16 : z_fp32;
    size_t i = (size_t)blockIdx.x * 256 + threadIdx.x;
    ((float4*)base)[i] = make_float4(0.f, 0.f, 0.f, 0.f);
    if (blockIdx.x == 0 && threadIdx.x < E_NUM) ((int*)counts)[threadIdx.x * CSTR] = 0;
}

template<int BF>
__device__ void router_body(const void* __restrict__ x, const void* __restrict__ Wr,
                            void* __restrict__ out_base,
                            int* __restrict__ counts, int* __restrict__ tok_list,
                            float* __restrict__ wt_list, float* __restrict__ sl)
{
    int t    = blockIdx.x;
    int lane = threadIdx.x;
    int e    = lane & 31;
    int half = lane >> 5;

    float acc = 0.f;
    size_t xoff = (size_t)t * H_DIM;
    int h0 = half * (H_DIM / 2);
    for (int h = h0; h < h0 + H_DIM / 2; ++h)
        acc = fmaf(ld<BF>(x, xoff + h), ld<BF>(Wr, (size_t)h * E_NUM + e), acc);
    acc += __shfl_down(acc, 32);

    if (lane < 32) {
        sl[e] = acc;
        size_t li = (size_t)T_TOK * H_DIM + (size_t)t * E_NUM + e;
        if (BF) ((hbf16*)out_base)[li] = __float2bfloat16(acc);
        else    ((float*)out_base)[li] = acc;
    }
    __syncthreads();

    if (lane == 0) {
        float s[E_NUM];
        #pragma unroll
        for (int i = 0; i < E_NUM; ++i) s[i] = sl[i];
        int   selE[4];
        float selL[4];
        int ns = 0;
        for (int g = 0; g < 2; ++g) {
            float sum0 = 0.f, sum1 = 0.f;
            #pragma unroll
            for (int j = 0; j < 8; ++j) {
                sum0 += s[(2*g)   * 8 + j];
                sum1 += s[(2*g+1) * 8 + j];
            }
            int bestSh = (sum1 > sum0) ? (2*g+1) : (2*g);
            int base = bestSh * 8;
            int i1 = 0;
            for (int j = 1; j < 8; ++j) if (s[base+j] > s[base+i1]) i1 = j;
            int i2 = -1;
            for (int j = 0; j < 8; ++j) {
                if (j == i1) continue;
                if (i2 < 0 || s[base+j] > s[base+i2]) i2 = j;
            }
            selE[ns] = base + i1; selL[ns] = s[base+i1]; ++ns;
            selE[ns] = base + i2; selL[ns] = s[base+i2]; ++ns;
        }
        float m = fmaxf(fmaxf(selL[0], selL[1]), fmaxf(selL[2], selL[3]));
        float w[4];
        float sum = 0.f;
        for (int j = 0; j < 4; ++j) { w[j] = expf(selL[j] - m); sum += w[j]; }
        float inv = 1.f / sum;
        for (int j = 0; j < 4; ++j) {
            int ee = selE[j];
            int pos = atomicAdd(&counts[ee * CSTR], 1);
            if (pos >= 0 && pos < CAP) {
                tok_list[ee * CAP + pos] = t;
                wt_list[ee * CAP + pos]  = w[j] * inv;
            }
        }
    }
}

__global__ __launch_bounds__(64) void router_kernel(
    const void* x, const void* Wr, void* out_base, const int* flag,
    int* counts, int* tok_list, float* wt_list)
{
    __shared__ float sl[E_NUM];
    if (*flag) router_body<1>(x, Wr, out_base, counts, tok_list, wt_list, sl);
    else       router_body<0>(x, Wr, out_base, counts, tok_list, wt_list, sl);
}

template<int BF>
__device__ void expert_body(const void* __restrict__ x,
                            const void* __restrict__ Wg, const void* __restrict__ Wu,
                            const void* __restrict__ Wd,
                            const int* __restrict__ counts, const int* __restrict__ tok_list,
                            const float* __restrict__ wt_list,
                            float* __restrict__ z, float* __restrict__ xsbuf)
{
    int e = blockIdx.x;
    int n = counts[e * CSTR];
    n = n < 0 ? 0 : (n > CAP ? CAP : n);
    int t0 = blockIdx.y * TT;
    if (t0 >= n) return;
    int tid = threadIdx.x;

    float (*xs)[H_DIM] = reinterpret_cast<float(*)[H_DIM]>(xsbuf);
    float (*hs)[I_DIM] = reinterpret_cast<float(*)[I_DIM]>(xsbuf);

    const int*   tl = tok_list + e * CAP;
    const float* wl = wt_list  + e * CAP;

    for (int idx = tid; idx < TT * H_DIM; idx += 256) {
        int tt = idx >> 10;
        int h  = idx & (H_DIM - 1);
        int it = t0 + tt;
        int tkn = (it < n) ? tl[it] : tl[t0];
        tkn = (tkn < 0) ? 0 : (tkn >= T_TOK ? T_TOK - 1 : tkn);
        xs[tt][h] = ld<BF>(x, (size_t)tkn * H_DIM + h);
    }
    __syncthreads();

    size_t wbase = (size_t)e * H_DIM * I_DIM + tid;
    float ag[TT], au[TT];
    #pragma unroll
    for (int tt = 0; tt < TT; ++tt) { ag[tt] = 0.f; au[tt] = 0.f; }

    for (int k = 0; k < H_DIM; k += 4) {
        float g0 = ld<BF>(Wg, wbase + (size_t)(k+0) * I_DIM);
        float g1 = ld<BF>(Wg, wbase + (size_t)(k+1) * I_DIM);
        float g2 = ld<BF>(Wg, wbase + (size_t)(k+2) * I_DIM);
        float g3 = ld<BF>(Wg, wbase + (size_t)(k+3) * I_DIM);
        float u0 = ld<BF>(Wu, wbase + (size_t)(k+0) * I_DIM);
        float u1 = ld<BF>(Wu, wbase + (size_t)(k+1) * I_DIM);
        float u2 = ld<BF>(Wu, wbase + (size_t)(k+2) * I_DIM);
        float u3 = ld<BF>(Wu, wbase + (size_t)(k+3) * I_DIM);
        #pragma unroll
        for (int tt = 0; tt < TT; ++tt) {
            float4 xv = *(const float4*)&xs[tt][k];
            ag[tt] = fmaf(xv.w, g3, fmaf(xv.z, g2, fmaf(xv.y, g1, fmaf(xv.x, g0, ag[tt]))));
            au[tt] = fmaf(xv.w, u3, fmaf(xv.z, u2, fmaf(xv.y, u1, fmaf(xv.x, u0, au[tt]))));
        }
    }
    float hval[TT];
    #pragma unroll
    for (int tt = 0; tt < TT; ++tt) {
        float g = ag[tt];
        hval[tt] = (g / (1.f + expf(-g))) * au[tt];
    }
    __syncthreads();
    #pragma unroll
    for (int tt = 0; tt < TT; ++tt) hs[tt][tid] = hval[tt];
    __syncthreads();

    size_t dbase = (size_t)e * I_DIM * O_DIM;
    float y0[TT], y1[TT];
    #pragma unroll
    for (int tt = 0; tt < TT; ++tt) { y0[tt] = 0.f; y1[tt] = 0.f; }

    for (int k = 0; k < I_DIM; k += 4) {
        float d00 = ld<BF>(Wd, dbase + (size_t)(k+0) * O_DIM + tid);
        float d01 = ld<BF>(Wd, dbase + (size_t)(k+1) * O_DIM + tid);
        float d02 = ld<BF>(Wd, dbase + (size_t)(k+2) * O_DIM + tid);
        float d03 = ld<BF>(Wd, dbase + (size_t)(k+3) * O_DIM + tid);
        float d10 = ld<BF>(Wd, dbase + (size_t)(k+0) * O_DIM + tid + 256);
        float d11 = ld<BF>(Wd, dbase + (size_t)(k+1) * O_DIM + tid + 256);
        float d12 = ld<BF>(Wd, dbase + (size_t)(k+2) * O_DIM + tid + 256);
        float d13 = ld<BF>(Wd, dbase + (size_t)(k+3) * O_DIM + tid + 256);
        #pragma unroll
        for (int tt = 0; tt < TT; ++tt) {
            float4 hv = *(const float4*)&hs[tt][k];
            y0[tt] = fmaf(hv.w, d03, fmaf(hv.z, d02, fmaf(hv.y, d01, fmaf(hv.x, d00, y0[tt]))));
            y1[tt] = fmaf(hv.w, d13, fmaf(hv.z, d12, fmaf(hv.y, d11, fmaf(hv.x, d10, y1[tt]))));
        }
    }

    int gsel = e >> 4;
    size_t colbase = (size_t)gsel * O_DIM;
    #pragma unroll
    for (int tt = 0; tt < TT; ++tt) {
        int it = t0 + tt;
        if (it < n) {
            float w  = wl[it];
            int tkn = tl[it];
            tkn = (tkn < 0) ? 0 : (tkn >= T_TOK ? T_TOK - 1 : tkn);
            atomicAdd(&z[(size_t)tkn * H_DIM + colbase + tid],       w * y0[tt]);
            atomicAdd(&z[(size_t)tkn * H_DIM + colbase + tid + 256], w * y1[tt]);
        }
    }
}

__global__ __launch_bounds__(256) void expert_kernel(
    const void* x, const void* Wg, const void* Wu, const void* Wd,
    const int* flag, const int* counts, const int* tok_list, const float* wt_list,
    float* z_fp32, float* z_bf16)
{
    __shared__ __align__(16) float xsbuf[TT * H_DIM];
    if (*flag) expert_body<1>(x, Wg, Wu, Wd, counts, tok_list, wt_list, z_bf16, xsbuf);
    else       expert_body<0>(x, Wg, Wu, Wd, counts, tok_list, wt_list, z_fp32, xsbuf);
}

template<int BF>
__device__ void wc_body(const float* __restrict__ z, const void* __restrict__ Wc,
                        void* __restrict__ out_base, float* __restrict__ psbuf)
{
    int t0  = blockIdx.x * WT;
    int tid = threadIdx.x;
    float (*ps)[H_DIM] = reinterpret_cast<float(*)[H_DIM]>(psbuf);

    for (int idx = tid; idx < WT * H_DIM; idx += 256) {
        int tt = idx >> 10;
        int h  = idx & (H_DIM - 1);
        ps[tt][h] = z[(size_t)(t0 + tt) * H_DIM + h];
    }
    __syncthreads();

    float acc[WT][4];
    #pragma unroll
    for (int tt = 0; tt < WT; ++tt)
        #pragma unroll
        for (int qq = 0; qq < 4; ++qq) acc[tt][qq] = 0.f;

    for (int k = 0; k < H_DIM; k += 2) {
        float c00 = ld<BF>(Wc, (size_t)(k+0) * H_DIM + tid);
        float c01 = ld<BF>(Wc, (size_t)(k+0) * H_DIM + tid + 256);
        float c02 = ld<BF>(Wc, (size_t)(k+0) * H_DIM + tid + 512);
        float c03 = ld<BF>(Wc, (size_t)(k+0) * H_DIM + tid + 768);
        float c10 = ld<BF>(Wc, (size_t)(k+1) * H_DIM + tid);
        float c11 = ld<BF>(Wc, (size_t)(k+1) * H_DIM + tid + 256);
        float c12 = ld<BF>(Wc, (size_t)(k+1) * H_DIM + tid + 512);
        float c13 = ld<BF>(Wc, (size_t)(k+1) * H_DIM + tid + 768);
        #pragma unroll
        for (int tt = 0; tt < WT; ++tt) {
            float2 pv = *(const float2*)&ps[tt][k];
            acc[tt][0] = fmaf(pv.y, c10, fmaf(pv.x, c00, acc[tt][0]));
            acc[tt][1] = fmaf(pv.y, c11, fmaf(pv.x, c01, acc[tt][1]));
            acc[tt][2] = fmaf(pv.y, c12, fmaf(pv.x, c02, acc[tt][2]));
            acc[tt][3] = fmaf(pv.y, c13, fmaf(pv.x, c03, acc[tt][3]));
        }
    }

    #pragma unroll
    for (int tt = 0; tt < WT; ++tt) {
        #pragma unroll
        for (int qq = 0; qq < 4; ++qq) {
            size_t o = (size_t)(t0 + tt) * H_DIM + tid + 256 * qq;
            if (BF) ((hbf16*)out_base)[o] = __float2bfloat16(acc[tt][qq]);
            else    ((float*)out_base)[o] = acc[tt][qq];
        }
    }
}

__global__ __launch_bounds__(256) void wc_kernel(
    const float* z_fp32, const float* z_bf16, const void* Wc,
    void* out_base, const int* flag)
{
    __shared__ __align__(16) float psbuf[WT * H_DIM];
    if (*flag) wc_body<1>(z_bf16, Wc, out_base, psbuf);
    else       wc_body<0>(z_fp32, Wc, out_base, psbuf);
}

// ---------------------------------------------------------------------------
extern "C" void kernel_launch(void* const* d_in, const int* in_sizes, int n_in,
                              void* d_out, int out_size, void* d_ws, size_t ws_size,
                              hipStream_t stream)
{
    (void)in_sizes; (void)n_in; (void)out_size;

    const void* x  = d_in[0];
    const void* Wr = d_in[1];
    const void* Wg = d_in[2];
    const void* Wu = d_in[3];
    const void* Wd = d_in[4];
    const void* Wc = d_in[5];

    char* ws = (char*)d_ws;
    int*   counts   = (int*)(ws + 0);          // padded: 32 counters x 128 B
    int*   flag     = (int*)(ws + 4096);
    int*   tok_list = (int*)(ws + 8192);
    float* wt_list  = (float*)(ws + 8192 + (size_t)E_NUM * CAP * 4);

    detect_kernel<<<1, 256, 0, stream>>>((const uint32_t*)x, flag, counts);

    if (ws_size >= ((size_t)58 << 20)) {
        ushort* ybuf = (ushort*)(ws + ((size_t)1  << 20));  // 8 MB bf16 [T][4][512]
        ushort* Wg_t = (ushort*)(ws + ((size_t)16 << 20));  // 16 MB
        ushort* Wu_t = (ushort*)(ws + ((size_t)32 << 20));  // 16 MB
        ushort* Wd_t = (ushort*)(ws + ((size_t)48 << 20));  // 8 MB
        ushort* Wc_t = (ushort*)(ws + ((size_t)56 << 20));  // 2 MB

        fused_cr_kernel<<<1024 + 5376, 256, 0, stream>>>(
            x, Wr, Wg, Wu, Wd, Wc, Wg_t, Wu_t, Wd_t, Wc_t,
            d_out, flag, counts, tok_list, wt_list);
        expert3_kernel<<<dim3(E_NUM, T_TOK / 16), 512, 0, stream>>>(
            x, Wg_t, Wu_t, Wd_t, flag, counts, tok_list, wt_list, ybuf);
        wc3_kernel<<<dim3(T_TOK / 16, 4), 512, 0, stream>>>(ybuf, Wc_t, d_out, flag);
    } else {
        float* z_bf16 = (float*)(ws + (1u << 20));
        float* z_fp32 = (float*)d_out;
        zero_kernel<<<T_TOK, 256, 0, stream>>>(z_fp32, z_bf16, flag, counts);
        router_kernel<<<T_TOK, 64, 0, stream>>>(x, Wr, d_out, flag, counts, tok_list, wt_list);
        expert_kernel<<<dim3(E_NUM, T_TOK / TT), 256, 0, stream>>>(
            x, Wg, Wu, Wd, flag, counts, tok_list, wt_list, z_fp32, z_bf16);
        wc_kernel<<<T_TOK / WT, 256, 0, stream>>>(z_fp32, z_bf16, Wc, d_out, flag);
    }
}

// Round 10
// 208.080 us; speedup vs baseline: 1.1112x; 1.1112x over previous
//
#include <hip/hip_runtime.h>
#include <hip/hip_bf16.h>
#include <math.h>
#include <stdint.h>

typedef __hip_bfloat16 hbf16;

#define T_TOK 2048
#define H_DIM 1024
#define E_NUM 32
#define I_DIM 256
#define O_DIM 512
#define CAP   2048
#define TT    16
#define WT    16
#define XSTR2 520    // xA/zA half-K row stride in ushorts (512 + 8 pad; 16B-aligned)
#define HSTR  264    // hsm row stride in ushorts (256 + 8 pad)
// r7: counts[32] = ONE 128B line; 8192 same-line atomics serialized (~60us).
// r8 validated the padded layout: total 241 -> 210us.
#define CSTR  32     // counts stride in ints (128 B)

typedef __bf16 bf16x8 __attribute__((ext_vector_type(8)));
typedef float  f32x4  __attribute__((ext_vector_type(4)));

__device__ __forceinline__ float b2f(hbf16 v) { return __bfloat162float(v); }
__device__ __forceinline__ float bb2f(ushort u) { return __uint_as_float((uint32_t)u << 16); }

__device__ __forceinline__ ushort f2b(float f) {   // fp32->bf16 RNE
    uint32_t u = __float_as_uint(f);
    return (ushort)((u + 0x7FFFu + ((u >> 16) & 1u)) >> 16);
}

template<int BF>
__device__ __forceinline__ float ld(const void* p, size_t i) {
    if (BF) return b2f(((const hbf16*)p)[i]);
    else    return ((const float*)p)[i];
}

__device__ __forceinline__ f32x4 mfma_bf16(bf16x8 a, bf16x8 b, f32x4 c) {
    return __builtin_amdgcn_mfma_f32_16x16x32_bf16(a, b, c, 0, 0, 0);
}

// Pin prefetch loads before the MFMA region (r3: compiler sank loads).
__device__ __forceinline__ void sched_fence() { __builtin_amdgcn_sched_barrier(0); }

// ---------------------------------------------------------------------------
// detect: dtype flag + zero counts (counts needed before router)
// ---------------------------------------------------------------------------
__global__ __launch_bounds__(256) void detect_kernel(
    const uint32_t* __restrict__ xw, int* __restrict__ flag, int* __restrict__ counts)
{
    __shared__ int cnt;
    if (threadIdx.x == 0) cnt = 0;
    if (threadIdx.x < E_NUM) counts[threadIdx.x * CSTR] = 0;
    __syncthreads();
    int c = 0;
    for (int i = threadIdx.x; i < 1024; i += 256) {
        int e = (xw[i] >> 7) & 0xFF;
        if (e >= 110 && e <= 140) c++;
    }
    atomicAdd(&cnt, c);
    __syncthreads();
    if (threadIdx.x == 0) *flag = (cnt > 512) ? 1 : 0;
}

// ===========================================================================
// FAST PATH (ws_size >= 58 MB)
// ===========================================================================

// ---- fused transpose+convert, 32(K) x 128(N) tiles, vectorized ----
// OUTPUT LAYOUT (fragment-blocked): element (n, k) of an E-slice goes to
//   dst[e*K*N + ((k>>5)*N + n)*32 + (k&31)]
__device__ void conv3_tile(const void* __restrict__ src, ushort* __restrict__ dst,
                           int bf, int K, int N, int b, float* __restrict__ sh)
{
    int tilesN = N >> 7, tilesK = K >> 5;
    int e  = b / (tilesK * tilesN);
    int r  = b % (tilesK * tilesN);
    int k0 = (r / tilesN) << 5;
    int n0 = (r % tilesN) << 7;
    size_t base = (size_t)e * K * N;
    int tid = threadIdx.x;
    {
        int row = tid >> 3, c0 = (tid & 7) * 16;
        if (!bf) {
            const float* sp = (const float*)src + base + (size_t)(k0 + row) * N + n0 + c0;
            #pragma unroll
            for (int i = 0; i < 4; ++i) {
                float4 v = *(const float4*)(sp + i * 4);
                sh[row * 132 + c0 + i*4 + 0] = v.x;
                sh[row * 132 + c0 + i*4 + 1] = v.y;
                sh[row * 132 + c0 + i*4 + 2] = v.z;
                sh[row * 132 + c0 + i*4 + 3] = v.w;
            }
        } else {
            const hbf16* sp = (const hbf16*)src + base + (size_t)(k0 + row) * N + n0 + c0;
            #pragma unroll
            for (int i = 0; i < 16; ++i) sh[row * 132 + c0 + i] = b2f(sp[i]);
        }
    }
    __syncthreads();
    {
        int nn = tid >> 1, kk = (tid & 1) * 16;
        union { ushort v[16]; uint4 u[2]; } R;
        #pragma unroll
        for (int i = 0; i < 16; ++i) R.v[i] = f2b(sh[(kk + i) * 132 + nn]);
        // blocked: ((k0>>5)*N + n)*32 + (kk..kk+15)
        ushort* dp = dst + base + ((size_t)(k0 >> 5) * N + (n0 + nn)) * 32 + kk;
        *(uint4*)dp       = R.u[0];
        *(uint4*)(dp + 8) = R.u[1];
    }
    __syncthreads();
}

// ---------------------------------------------------------------------------
// router body (r6 structure): 2 tokens, 256 thr. x staged once, K split
// 8-ways (thread=(half,e)), Wr direct from global, LDS reduce, tail.
// Runs as blocks 0..1023 of the fused kernel, overlapped with convert.
// ---------------------------------------------------------------------------
template<int BF>
__device__ void router3_body(const void* __restrict__ x, const void* __restrict__ Wr,
                             void* __restrict__ out_base,
                             int* __restrict__ counts, int* __restrict__ tok_list,
                             float* __restrict__ wt_list,
                             float* __restrict__ xs, float* __restrict__ sl,
                             float* __restrict__ sf, int t0)
{
    int tid  = threadIdx.x;
    int e    = tid & 31;
    int half = tid >> 5;          // 0..7 (K chunk)

    // ---- stage x[2][1024] -> fp32 LDS (128 thr/row, 8 floats each) ----
    {
        int t = tid >> 7;           // 0..1
        int c = (tid & 127) * 8;
        if (!BF) {
            const float* xp = (const float*)x + (size_t)(t0 + t) * H_DIM + c;
            *(float4*)&xs[t*1024 + c]     = *(const float4*)xp;
            *(float4*)&xs[t*1024 + c + 4] = *(const float4*)(xp + 4);
        } else {
            const hbf16* xp = (const hbf16*)x + (size_t)(t0 + t) * H_DIM + c;
            #pragma unroll
            for (int j = 0; j < 8; ++j) xs[t*1024 + c + j] = b2f(xp[j]);
        }
    }
    __syncthreads();

    // ---- 128-k partial dot for both tokens; Wr direct from global ----
    float a0 = 0.f, a1 = 0.f;
    int kbase = half * 128;
    const float* xr0 = &xs[kbase];
    const float* xr1 = &xs[1024 + kbase];
    #pragma unroll 8
    for (int k = 0; k < 128; ++k) {
        float w = ld<BF>(Wr, (size_t)(kbase + k) * E_NUM + e);
        a0 = fmaf(xr0[k], w, a0);
        a1 = fmaf(xr1[k], w, a1);
    }
    sl[(0*8 + half)*32 + e] = a0;
    sl[(1*8 + half)*32 + e] = a1;
    __syncthreads();

    // ---- reduce 8 partials, write logits ----
    if (tid < 64) {
        int t  = tid >> 5;
        int ee = tid & 31;
        float s = 0.f;
        #pragma unroll
        for (int h = 0; h < 8; ++h) s += sl[(t*8 + h)*32 + ee];
        sf[t*32 + ee] = s;
        size_t li = (size_t)T_TOK * H_DIM + (size_t)(t0 + t) * E_NUM + ee;
        if (BF) ((hbf16*)out_base)[li] = __float2bfloat16(s);
        else    ((float*)out_base)[li] = s;
    }
    __syncthreads();

    // ---- selection tail (1 thread per token) ----
    if (tid < 2) {
        int t = t0 + tid;
        float s[E_NUM];
        #pragma unroll
        for (int i = 0; i < E_NUM; ++i) s[i] = sf[tid * 32 + i];

        int   selE[4];
        float selL[4];
        int ns = 0;
        for (int g = 0; g < 2; ++g) {
            float sum0 = 0.f, sum1 = 0.f;
            #pragma unroll
            for (int j = 0; j < 8; ++j) {
                sum0 += s[(2*g)   * 8 + j];
                sum1 += s[(2*g+1) * 8 + j];
            }
            int bestSh = (sum1 > sum0) ? (2*g+1) : (2*g);
            int base = bestSh * 8;
            int i1 = 0;
            for (int j = 1; j < 8; ++j) if (s[base+j] > s[base+i1]) i1 = j;
            int i2 = -1;
            for (int j = 0; j < 8; ++j) {
                if (j == i1) continue;
                if (i2 < 0 || s[base+j] > s[base+i2]) i2 = j;
            }
            selE[ns] = base + i1; selL[ns] = s[base+i1]; ++ns;
            selE[ns] = base + i2; selL[ns] = s[base+i2]; ++ns;
        }
        float m = fmaxf(fmaxf(selL[0], selL[1]), fmaxf(selL[2], selL[3]));
        float w[4];
        float sum = 0.f;
        for (int j = 0; j < 4; ++j) { w[j] = expf(selL[j] - m); sum += w[j]; }
        float inv = 1.f / sum;
        for (int j = 0; j < 4; ++j) {
            int ee = selE[j];
            int pos = atomicAdd(&counts[ee * CSTR], 1);   // padded: own cache line
            if (pos >= 0 && pos < CAP) {
                tok_list[ee * CAP + pos] = t | (j << 11);   // pack slot
                wt_list[ee * CAP + pos]  = w[j] * inv;
            }
        }
    }
}

// ---------------------------------------------------------------------------
// FUSED convert + router: 6400 blocks x 256 thr. Blocks 0..1023 = router
// (latency-bound long pole, starts at t=0); blocks 1024..6399 = weight
// convert tiles (BW-bound, fills the machine underneath).
// ---------------------------------------------------------------------------
__global__ __launch_bounds__(256) void fused_cr_kernel(
    const void* x, const void* Wr,
    const void* Wg, const void* Wu, const void* Wd, const void* Wc,
    ushort* Wg_t, ushort* Wu_t, ushort* Wd_t, ushort* Wc_t,
    void* out_base, const int* __restrict__ flag,
    int* counts, int* tok_list, float* wt_list)
{
    __shared__ __align__(16) float sh[32 * 132];   // 16896 B, both paths
    int b = blockIdx.x;
    if (b < 1024) {
        float* xs = sh;             // 2048 floats
        float* sl = sh + 2048;      // 512 floats
        float* sf = sh + 2560;      // 64 floats   (2624 < 4224 total)
        if (*flag) router3_body<1>(x, Wr, out_base, counts, tok_list, wt_list,
                                   xs, sl, sf, b * 2);
        else       router3_body<0>(x, Wr, out_base, counts, tok_list, wt_list,
                                   xs, sl, sf, b * 2);
    } else {
        int bb = b - 1024;
        int bf = *flag;
        if      (bb < 2048) conv3_tile(Wg, Wg_t, bf, 1024,  256, bb,        sh);
        else if (bb < 4096) conv3_tile(Wu, Wu_t, bf, 1024,  256, bb - 2048, sh);
        else if (bb < 5120) conv3_tile(Wd, Wd_t, bf,  256,  512, bb - 4096, sh);
        else                conv3_tile(Wc, Wc_t, bf, 1024, 1024, bb - 5120, sh);
    }
}

// ---------------------------------------------------------------------------
// expert3 (16 waves, M=32): 1024 thr, 32 tokens/block, grid (32, 64).
// r9 post-mortem: M=16 halved weight reuse (FETCH 42->62MB) and regressed.
// r8 breakdown: per-block 127Kcy = 13Kcy MFMA + ~114Kcy serialized load
// latency (~700cy/round x 160 rounds/wave) -- depth-1 prefetch only hides
// the ~80cy of MFMA. Fix: keep M=32 (same traffic) but DOUBLE wave-level
// concurrency: 16 waves x half-width column slices (gate/up 16 cols/wave,
// down 32 cols/wave). 4 waves/SIMD interleave the stalls. launch_bounds
// (1024,4) pins VGPR cap at 128 (r1's unhinted 64-VGPR spill avoided);
// est. peak ~113 VGPR. Spill canary: WRITE_SIZE >> 8MB.
// ---------------------------------------------------------------------------
template<int BF>
__device__ void expert3_body(const void* __restrict__ x,
    const ushort* __restrict__ Wg_t, const ushort* __restrict__ Wu_t,
    const ushort* __restrict__ Wd_t,
    const int* __restrict__ counts, const int* __restrict__ tok_list,
    const float* __restrict__ wt_list, ushort* __restrict__ ybuf,
    ushort* __restrict__ xA, ushort* __restrict__ hsm,
    int* __restrict__ tokid, float* __restrict__ twt, int* __restrict__ tslot)
{
    int e = blockIdx.x;
    int n = counts[e * CSTR]; n = n < 0 ? 0 : (n > CAP ? CAP : n);
    int t0 = blockIdx.y * 32;
    if (t0 >= n) return;
    int tid  = threadIdx.x;
    int lane = tid & 63, wv = tid >> 6;        // wv 0..15
    int q = lane >> 4, l15 = lane & 15;

    if (tid < 32) {
        int it = t0 + tid;
        int id; float ww;
        if (it < n) { id = tok_list[e*CAP + it]; ww = wt_list[e*CAP + it]; }
        else        { id = tok_list[e*CAP + t0]; ww = 0.f; }
        tokid[tid] = id & 2047;
        tslot[tid] = (id >> 11) & 3;
        twt[tid]   = ww;
    }
    __syncthreads();

    // blocked-layout frag base: (col)*32 + q*8 ; gate/up frag(idx) at +idx*8192
    const ushort* Bg0 = Wg_t + (size_t)e * (H_DIM * I_DIM) + (wv*16 + l15) * 32 + q*8;
    const ushort* Bu0 = Wu_t + (size_t)e * (H_DIM * I_DIM) + (wv*16 + l15) * 32 + q*8;

    f32x4 Cg[2], Cu[2];     // [m] token halves
    Cg[0] = (f32x4)0.f; Cg[1] = (f32x4)0.f;
    Cu[0] = (f32x4)0.f; Cu[1] = (f32x4)0.f;

    bf16x8 bg[2][4], bu[2][4];     // dbuf: 16 frags = 64 VGPR
    #pragma unroll
    for (int ig = 0; ig < 4; ++ig) {
        bg[0][ig] = *(const bf16x8*)(Bg0 + (size_t)ig*8192);
        bu[0][ig] = *(const bf16x8*)(Bu0 + (size_t)ig*8192);
    }
    sched_fence();   // pin initial preload issue here

    // ---- gate/up over two K-halves; xA restaged per half ----
    #pragma unroll
    for (int hk = 0; hk < 2; ++hk) {
        if (hk) __syncthreads();   // all waves done reading half-0 xA

        // stage x[32][hk*512 .. hk*512+512) -> bf16 LDS (32 thr/row)
        {
            int row = tid >> 5;          // 0..31
            int kb  = (tid & 31) * 8;
            size_t srow = (size_t)tokid[row] * H_DIM + hk * 512;
            #pragma unroll
            for (int c = 0; c < 2; ++c) {
                int k = kb + c * 256;
                union { ushort v[8]; uint4 u; } U;
                if (BF) {
                    U.u = *(const uint4*)((const ushort*)x + srow + k);
                } else {
                    const float* xp = (const float*)x + srow + k;
                    float4 a = *(const float4*)xp;
                    float4 b = *(const float4*)(xp + 4);
                    U.v[0]=f2b(a.x); U.v[1]=f2b(a.y); U.v[2]=f2b(a.z); U.v[3]=f2b(a.w);
                    U.v[4]=f2b(b.x); U.v[5]=f2b(b.y); U.v[6]=f2b(b.z); U.v[7]=f2b(b.w);
                }
                *(uint4*)&xA[row * XSTR2 + k] = U.u;
            }
        }
        __syncthreads();

        #pragma unroll
        for (int g2 = 0; g2 < 4; ++g2) {
            int grp = hk * 4 + g2;
            int cb  = grp & 1;
            if (grp < 7) {
                #pragma unroll
                for (int ig = 0; ig < 4; ++ig) {
                    int idx = (grp + 1) * 4 + ig;
                    bg[cb^1][ig] = *(const bf16x8*)(Bg0 + (size_t)idx*8192);
                    bu[cb^1][ig] = *(const bf16x8*)(Bu0 + (size_t)idx*8192);
                }
            }
            sched_fence();   // prefetch for grp+1 must be ISSUED before these MFMAs
            #pragma unroll
            for (int ig = 0; ig < 4; ++ig) {
                int kl = (g2 * 4 + ig) * 32;     // local K offset within half
                bf16x8 A0 = *(const bf16x8*)&xA[(l15)      * XSTR2 + kl + q*8];
                bf16x8 A1 = *(const bf16x8*)&xA[(16 + l15) * XSTR2 + kl + q*8];
                Cg[0] = mfma_bf16(A0, bg[cb][ig], Cg[0]);
                Cg[1] = mfma_bf16(A1, bg[cb][ig], Cg[1]);
                Cu[0] = mfma_bf16(A0, bu[cb][ig], Cu[0]);
                Cu[1] = mfma_bf16(A1, bu[cb][ig], Cu[1]);
            }
        }
    }

    // ---- down B preload (32 cols/wave, j<2) issued BEFORE the silu/store ----
    const ushort* Bd0 = Wd_t + (size_t)e * (I_DIM * O_DIM) + (wv*32 + l15) * 32 + q*8;
    bf16x8 bd[8][2];     // 16 frags = 64 VGPR (bg/bu dead by here)
    #pragma unroll
    for (int kc = 0; kc < 8; ++kc)
        #pragma unroll
        for (int j = 0; j < 2; ++j)
            bd[kc][j] = *(const bf16x8*)(Bd0 + (size_t)kc*16384 + j*512);
    sched_fence();   // keep the preload in flight across silu + barrier

    // ---- h = silu(g)*u -> hsm (col = wv*16 + l15) ----
    #pragma unroll
    for (int m = 0; m < 2; ++m)
        #pragma unroll
        for (int r = 0; r < 4; ++r) {
            float g = Cg[m][r], u = Cu[m][r];
            float h = (g / (1.f + expf(-g))) * u;
            hsm[(m*16 + q*4 + r) * HSTR + wv*16 + l15] = f2b(h);
        }
    __syncthreads();

    // ---- down: K=256 = 8 kc ----
    f32x4 Cd[2][2];   // [m][j]
    Cd[0][0] = (f32x4)0.f; Cd[0][1] = (f32x4)0.f;
    Cd[1][0] = (f32x4)0.f; Cd[1][1] = (f32x4)0.f;
    #pragma unroll
    for (int kc = 0; kc < 8; ++kc) {
        bf16x8 A0 = *(const bf16x8*)&hsm[(l15)      * HSTR + kc*32 + q*8];
        bf16x8 A1 = *(const bf16x8*)&hsm[(16 + l15) * HSTR + kc*32 + q*8];
        #pragma unroll
        for (int j = 0; j < 2; ++j) {
            Cd[0][j] = mfma_bf16(A0, bd[kc][j], Cd[0][j]);
            Cd[1][j] = mfma_bf16(A1, bd[kc][j], Cd[1][j]);
        }
    }

    // ---- store y = w * down to ybuf[t][slot][col], bf16, guarded ----
    #pragma unroll
    for (int m = 0; m < 2; ++m)
        #pragma unroll
        for (int r = 0; r < 4; ++r) {
            int row = m*16 + q*4 + r;
            if (t0 + row < n) {
                float ww = twt[row];
                size_t base = ((size_t)tokid[row] * 4 + tslot[row]) * O_DIM;
                #pragma unroll
                for (int j = 0; j < 2; ++j)
                    ybuf[base + wv*32 + j*16 + l15] = f2b(ww * Cd[m][j][r]);
            }
        }
}

__global__ __launch_bounds__(1024, 4) void expert3_kernel(
    const void* x, const ushort* Wg_t, const ushort* Wu_t, const ushort* Wd_t,
    const int* flag, const int* counts, const int* tok_list, const float* wt_list,
    ushort* ybuf)
{
    __shared__ ushort xA[32 * XSTR2];
    __shared__ ushort hsm[32 * HSTR];
    __shared__ int    tokid[32];
    __shared__ float  twt[32];
    __shared__ int    tslot[32];
    if (*flag) expert3_body<1>(x, Wg_t, Wu_t, Wd_t, counts, tok_list, wt_list,
                               ybuf, xA, hsm, tokid, twt, tslot);
    else       expert3_body<0>(x, Wg_t, Wu_t, Wd_t, counts, tok_list, wt_list,
                               ybuf, xA, hsm, tokid, twt, tslot);
}

// ---------------------------------------------------------------------------
// wc3 (16 waves, M=32): out = z @ Wc, z rows from ybuf slot sums. 1024 thr,
// M=32, N=256 (16 cols/wave), grid (64, 4). Same de-serialization.
// ---------------------------------------------------------------------------
template<int BF>
__device__ void wc3_body(const ushort* __restrict__ ybuf, const ushort* __restrict__ Wc_t,
                         void* __restrict__ out_base, ushort* __restrict__ zA)
{
    int m0  = blockIdx.x * 32;
    int n0  = blockIdx.y * 256;
    int tid = threadIdx.x;
    int lane = tid & 63, wv = tid >> 6;     // wv 0..15
    int q = lane >> 4, l15 = lane & 15;

    // blocked: frag(idx) at Bc0 + idx*32768
    const ushort* Bc0 = Wc_t + (size_t)(n0 + wv*16 + l15) * 32 + q*8;
    f32x4 C[2];          // [m]
    C[0] = (f32x4)0.f; C[1] = (f32x4)0.f;

    bf16x8 bc[2][4];     // dbuf: 8 frags
    #pragma unroll
    for (int ig = 0; ig < 4; ++ig)
        bc[0][ig] = *(const bf16x8*)(Bc0 + (size_t)ig*32768);
    sched_fence();

    #pragma unroll
    for (int hk = 0; hk < 2; ++hk) {
        if (hk) __syncthreads();   // all waves done reading half-0 zA

        // ---- stage z[32][half] = slot-pair sums, bf16 (32 thr/row) ----
        {
            int row = tid >> 5;          // 0..31
            int kb  = (tid & 31) * 8;
            int t = m0 + row;
            int s0 = hk ? 2 : 0;
            #pragma unroll
            for (int c = 0; c < 2; ++c) {
                int hl = kb + c * 256;
                const ushort* p0 = ybuf + ((size_t)t * 4 + s0) * O_DIM + hl;
                union { ushort v[8]; uint4 u; } A, B, R;
                A.u = *(const uint4*)p0;
                B.u = *(const uint4*)(p0 + O_DIM);
                #pragma unroll
                for (int i = 0; i < 8; ++i) R.v[i] = f2b(bb2f(A.v[i]) + bb2f(B.v[i]));
                *(uint4*)&zA[row * XSTR2 + hl] = R.u;
            }
        }
        __syncthreads();

        #pragma unroll
        for (int g2 = 0; g2 < 4; ++g2) {
            int grp = hk * 4 + g2;
            int cb  = grp & 1;
            if (grp < 7) {
                #pragma unroll
                for (int ig = 0; ig < 4; ++ig) {
                    int idx = (grp + 1) * 4 + ig;
                    bc[cb^1][ig] = *(const bf16x8*)(Bc0 + (size_t)idx*32768);
                }
            }
            sched_fence();   // prefetch issued before MFMAs
            #pragma unroll
            for (int ig = 0; ig < 4; ++ig) {
                int kl = (g2 * 4 + ig) * 32;
                bf16x8 A0 = *(const bf16x8*)&zA[(l15)      * XSTR2 + kl + q*8];
                bf16x8 A1 = *(const bf16x8*)&zA[(16 + l15) * XSTR2 + kl + q*8];
                C[0] = mfma_bf16(A0, bc[cb][ig], C[0]);
                C[1] = mfma_bf16(A1, bc[cb][ig], C[1]);
            }
        }
    }

    #pragma unroll
    for (int m = 0; m < 2; ++m)
        #pragma unroll
        for (int r = 0; r < 4; ++r) {
            int row = m0 + m*16 + q*4 + r;
            int col = n0 + wv*16 + l15;
            size_t o = (size_t)row * H_DIM + col;
            if (BF) ((hbf16*)out_base)[o] = __float2bfloat16(C[m][r]);
            else    ((float*)out_base)[o] = C[m][r];
        }
}

__global__ __launch_bounds__(1024, 4) void wc3_kernel(
    const ushort* ybuf, const ushort* Wc_t, void* out_base, const int* flag)
{
    __shared__ ushort zA[32 * XSTR2];
    if (*flag) wc3_body<1>(ybuf, Wc_t, out_base, zA);
    else       wc3_body<0>(ybuf, Wc_t, out_base, zA);
}

// ===========================================================================
// FALLBACK PATH (round-4, known passing) — only if ws is small
// ===========================================================================

__global__ __launch_bounds__(256) void zero_kernel(
    float* __restrict__ z_fp32, float* __restrict__ z_bf16,
    const int* __restrict__ flag, int* __restrict__ counts)
{
    float* base = (*flag) ? z_bf16 : z_fp32;
    size_t i = (size_t)blockIdx.x * 256 + threadIdx.x;
    ((float4*)base)[i] = make_float4(0.f, 0.f, 0.f, 0.f);
    if (blockIdx.x == 0 && threadIdx.x < E_NUM) ((int*)counts)[threadIdx.x * CSTR] = 0;
}

template<int BF>
__device__ void router_body(const void* __restrict__ x, const void* __restrict__ Wr,
                            void* __restrict__ out_base,
                            int* __restrict__ counts, int* __restrict__ tok_list,
                            float* __restrict__ wt_list, float* __restrict__ sl)
{
    int t    = blockIdx.x;
    int lane = threadIdx.x;
    int e    = lane & 31;
    int half = lane >> 5;

    float acc = 0.f;
    size_t xoff = (size_t)t * H_DIM;
    int h0 = half * (H_DIM / 2);
    for (int h = h0; h < h0 + H_DIM / 2; ++h)
        acc = fmaf(ld<BF>(x, xoff + h), ld<BF>(Wr, (size_t)h * E_NUM + e), acc);
    acc += __shfl_down(acc, 32);

    if (lane < 32) {
        sl[e] = acc;
        size_t li = (size_t)T_TOK * H_DIM + (size_t)t * E_NUM + e;
        if (BF) ((hbf16*)out_base)[li] = __float2bfloat16(acc);
        else    ((float*)out_base)[li] = acc;
    }
    __syncthreads();

    if (lane == 0) {
        float s[E_NUM];
        #pragma unroll
        for (int i = 0; i < E_NUM; ++i) s[i] = sl[i];
        int   selE[4];
        float selL[4];
        int ns = 0;
        for (int g = 0; g < 2; ++g) {
            float sum0 = 0.f, sum1 = 0.f;
            #pragma unroll
            for (int j = 0; j < 8; ++j) {
                sum0 += s[(2*g)   * 8 + j];
                sum1 += s[(2*g+1) * 8 + j];
            }
            int bestSh = (sum1 > sum0) ? (2*g+1) : (2*g);
            int base = bestSh * 8;
            int i1 = 0;
            for (int j = 1; j < 8; ++j) if (s[base+j] > s[base+i1]) i1 = j;
            int i2 = -1;
            for (int j = 0; j < 8; ++j) {
                if (j == i1) continue;
                if (i2 < 0 || s[base+j] > s[base+i2]) i2 = j;
            }
            selE[ns] = base + i1; selL[ns] = s[base+i1]; ++ns;
            selE[ns] = base + i2; selL[ns] = s[base+i2]; ++ns;
        }
        float m = fmaxf(fmaxf(selL[0], selL[1]), fmaxf(selL[2], selL[3]));
        float w[4];
        float sum = 0.f;
        for (int j = 0; j < 4; ++j) { w[j] = expf(selL[j] - m); sum += w[j]; }
        float inv = 1.f / sum;
        for (int j = 0; j < 4; ++j) {
            int ee = selE[j];
            int pos = atomicAdd(&counts[ee * CSTR], 1);
            if (pos >= 0 && pos < CAP) {
                tok_list[ee * CAP + pos] = t;
                wt_list[ee * CAP + pos]  = w[j] * inv;
            }
        }
    }
}

__global__ __launch_bounds__(64) void router_kernel(
    const void* x, const void* Wr, void* out_base, const int* flag,
    int* counts, int* tok_list, float* wt_list)
{
    __shared__ float sl[E_NUM];
    if (*flag) router_body<1>(x, Wr, out_base, counts, tok_list, wt_list, sl);
    else       router_body<0>(x, Wr, out_base, counts, tok_list, wt_list, sl);
}

template<int BF>
__device__ void expert_body(const void* __restrict__ x,
                            const void* __restrict__ Wg, const void* __restrict__ Wu,
                            const void* __restrict__ Wd,
                            const int* __restrict__ counts, const int* __restrict__ tok_list,
                            const float* __restrict__ wt_list,
                            float* __restrict__ z, float* __restrict__ xsbuf)
{
    int e = blockIdx.x;
    int n = counts[e * CSTR];
    n = n < 0 ? 0 : (n > CAP ? CAP : n);
    int t0 = blockIdx.y * TT;
    if (t0 >= n) return;
    int tid = threadIdx.x;

    float (*xs)[H_DIM] = reinterpret_cast<float(*)[H_DIM]>(xsbuf);
    float (*hs)[I_DIM] = reinterpret_cast<float(*)[I_DIM]>(xsbuf);

    const int*   tl = tok_list + e * CAP;
    const float* wl = wt_list  + e * CAP;

    for (int idx = tid; idx < TT * H_DIM; idx += 256) {
        int tt = idx >> 10;
        int h  = idx & (H_DIM - 1);
        int it = t0 + tt;
        int tkn = (it < n) ? tl[it] : tl[t0];
        tkn = (tkn < 0) ? 0 : (tkn >= T_TOK ? T_TOK - 1 : tkn);
        xs[tt][h] = ld<BF>(x, (size_t)tkn * H_DIM + h);
    }
    __syncthreads();

    size_t wbase = (size_t)e * H_DIM * I_DIM + tid;
    float ag[TT], au[TT];
    #pragma unroll
    for (int tt = 0; tt < TT; ++tt) { ag[tt] = 0.f; au[tt] = 0.f; }

    for (int k = 0; k < H_DIM; k += 4) {
        float g0 = ld<BF>(Wg, wbase + (size_t)(k+0) * I_DIM);
        float g1 = ld<BF>(Wg, wbase + (size_t)(k+1) * I_DIM);
        float g2 = ld<BF>(Wg, wbase + (size_t)(k+2) * I_DIM);
        float g3 = ld<BF>(Wg, wbase + (size_t)(k+3) * I_DIM);
        float u0 = ld<BF>(Wu, wbase + (size_t)(k+0) * I_DIM);
        float u1 = ld<BF>(Wu, wbase + (size_t)(k+1) * I_DIM);
        float u2 = ld<BF>(Wu, wbase + (size_t)(k+2) * I_DIM);
        float u3 = ld<BF>(Wu, wbase + (size_t)(k+3) * I_DIM);
        #pragma unroll
        for (int tt = 0; tt < TT; ++tt) {
            float4 xv = *(const float4*)&xs[tt][k];
            ag[tt] = fmaf(xv.w, g3, fmaf(xv.z, g2, fmaf(xv.y, g1, fmaf(xv.x, g0, ag[tt]))));
            au[tt] = fmaf(xv.w, u3, fmaf(xv.z, u2, fmaf(xv.y, u1, fmaf(xv.x, u0, au[tt]))));
        }
    }
    float hval[TT];
    #pragma unroll
    for (int tt = 0; tt < TT; ++tt) {
        float g = ag[tt];
        hval[tt] = (g / (1.f + expf(-g))) * au[tt];
    }
    __syncthreads();
    #pragma unroll
    for (int tt = 0; tt < TT; ++tt) hs[tt][tid] = hval[tt];
    __syncthreads();

    size_t dbase = (size_t)e * I_DIM * O_DIM;
    float y0[TT], y1[TT];
    #pragma unroll
    for (int tt = 0; tt < TT; ++tt) { y0[tt] = 0.f; y1[tt] = 0.f; }

    for (int k = 0; k < I_DIM; k += 4) {
        float d00 = ld<BF>(Wd, dbase + (size_t)(k+0) * O_DIM + tid);
        float d01 = ld<BF>(Wd, dbase + (size_t)(k+1) * O_DIM + tid);
        float d02 = ld<BF>(Wd, dbase + (size_t)(k+2) * O_DIM + tid);
        float d03 = ld<BF>(Wd, dbase + (size_t)(k+3) * O_DIM + tid);
        float d10 = ld<BF>(Wd, dbase + (size_t)(k+0) * O_DIM + tid + 256);
        float d11 = ld<BF>(Wd, dbase + (size_t)(k+1) * O_DIM + tid + 256);
        float d12 = ld<BF>(Wd, dbase + (size_t)(k+2) * O_DIM + tid + 256);
        float d13 = ld<BF>(Wd, dbase + (size_t)(k+3) * O_DIM + tid + 256);
        #pragma unroll
        for (int tt = 0; tt < TT; ++tt) {
            float4 hv = *(const float4*)&hs[tt][k];
            y0[tt] = fmaf(hv.w, d03, fmaf(hv.z, d02, fmaf(hv.y, d01, fmaf(hv.x, d00, y0[tt]))));
            y1[tt] = fmaf(hv.w, d13, fmaf(hv.z, d12, fmaf(hv.y, d11, fmaf(hv.x, d10, y1[tt]))));
        }
    }

    int gsel = e >> 4;
    size_t colbase = (size_t)gsel * O_DIM;
    #pragma unroll
    for (int tt = 0; tt < TT; ++tt) {
        int it = t0 + tt;
        if (it < n) {
            float w  = wl[it];
            int tkn = tl[it];
            tkn = (tkn < 0) ? 0 : (tkn >= T_TOK ? T_TOK - 1 : tkn);
            atomicAdd(&z[(size_t)tkn * H_DIM + colbase + tid],       w * y0[tt]);
            atomicAdd(&z[(size_t)tkn * H_DIM + colbase + tid + 256], w * y1[tt]);
        }
    }
}

__global__ __launch_bounds__(256) void expert_kernel(
    const void* x, const void* Wg, const void* Wu, const void* Wd,
    const int* flag, const int* counts, const int* tok_list, const float* wt_list,
    float* z_fp32, float* z_bf16)
{
    __shared__ __align__(16) float xsbuf[TT * H_DIM];
    if (*flag) expert_body<1>(x, Wg, Wu, Wd, counts, tok_list, wt_list, z_bf16, xsbuf);
    else       expert_body<0>(x, Wg, Wu, Wd, counts, tok_list, wt_list, z_fp32, xsbuf);
}

template<int BF>
__device__ void wc_body(const float* __restrict__ z, const void* __restrict__ Wc,
                        void* __restrict__ out_base, float* __restrict__ psbuf)
{
    int t0  = blockIdx.x * WT;
    int tid = threadIdx.x;
    float (*ps)[H_DIM] = reinterpret_cast<float(*)[H_DIM]>(psbuf);

    for (int idx = tid; idx < WT * H_DIM; idx += 256) {
        int tt = idx >> 10;
        int h  = idx & (H_DIM - 1);
        ps[tt][h] = z[(size_t)(t0 + tt) * H_DIM + h];
    }
    __syncthreads();

    float acc[WT][4];
    #pragma unroll
    for (int tt = 0; tt < WT; ++tt)
        #pragma unroll
        for (int qq = 0; qq < 4; ++qq) acc[tt][qq] = 0.f;

    for (int k = 0; k < H_DIM; k += 2) {
        float c00 = ld<BF>(Wc, (size_t)(k+0) * H_DIM + tid);
        float c01 = ld<BF>(Wc, (size_t)(k+0) * H_DIM + tid + 256);
        float c02 = ld<BF>(Wc, (size_t)(k+0) * H_DIM + tid + 512);
        float c03 = ld<BF>(Wc, (size_t)(k+0) * H_DIM + tid + 768);
        float c10 = ld<BF>(Wc, (size_t)(k+1) * H_DIM + tid);
        float c11 = ld<BF>(Wc, (size_t)(k+1) * H_DIM + tid + 256);
        float c12 = ld<BF>(Wc, (size_t)(k+1) * H_DIM + tid + 512);
        float c13 = ld<BF>(Wc, (size_t)(k+1) * H_DIM + tid + 768);
        #pragma unroll
        for (int tt = 0; tt < WT; ++tt) {
            float2 pv = *(const float2*)&ps[tt][k];
            acc[tt][0] = fmaf(pv.y, c10, fmaf(pv.x, c00, acc[tt][0]));
            acc[tt][1] = fmaf(pv.y, c11, fmaf(pv.x, c01, acc[tt][1]));
            acc[tt][2] = fmaf(pv.y, c12, fmaf(pv.x, c02, acc[tt][2]));
            acc[tt][3] = fmaf(pv.y, c13, fmaf(pv.x, c03, acc[tt][3]));
        }
    }

    #pragma unroll
    for (int tt = 0; tt < WT; ++tt) {
        #pragma unroll
        for (int qq = 0; qq < 4; ++qq) {
            size_t o = (size_t)(t0 + tt) * H_DIM + tid + 256 * qq;
            if (BF) ((hbf16*)out_base)[o] = __float2bfloat16(acc[tt][qq]);
            else    ((float*)out_base)[o] = acc[tt][qq];
        }
    }
}

__global__ __launch_bounds__(256) void wc_kernel(
    const float* z_fp32, const float* z_bf16, const void* Wc,
    void* out_base, const int* flag)
{
    __shared__ __align__(16) float psbuf[WT * H_DIM];
    if (*flag) wc_body<1>(z_bf16, Wc, out_base, psbuf);
    else       wc_body<0>(z_fp32, Wc, out_base, psbuf);
}

// ---------------------------------------------------------------------------
extern "C" void kernel_launch(void* const* d_in, const int* in_sizes, int n_in,
                              void* d_out, int out_size, void* d_ws, size_t ws_size,
                              hipStream_t stream)
{
    (void)in_sizes; (void)n_in; (void)out_size;

    const void* x  = d_in[0];
    const void* Wr = d_in[1];
    const void* Wg = d_in[2];
    const void* Wu = d_in[3];
    const void* Wd = d_in[4];
    const void* Wc = d_in[5];

    char* ws = (char*)d_ws;
    int*   counts   = (int*)(ws + 0);          // padded: 32 counters x 128 B
    int*   flag     = (int*)(ws + 4096);
    int*   tok_list = (int*)(ws + 8192);
    float* wt_list  = (float*)(ws + 8192 + (size_t)E_NUM * CAP * 4);

    detect_kernel<<<1, 256, 0, stream>>>((const uint32_t*)x, flag, counts);

    if (ws_size >= ((size_t)58 << 20)) {
        ushort* ybuf = (ushort*)(ws + ((size_t)1  << 20));  // 8 MB bf16 [T][4][512]
        ushort* Wg_t = (ushort*)(ws + ((size_t)16 << 20));  // 16 MB
        ushort* Wu_t = (ushort*)(ws + ((size_t)32 << 20));  // 16 MB
        ushort* Wd_t = (ushort*)(ws + ((size_t)48 << 20));  // 8 MB
        ushort* Wc_t = (ushort*)(ws + ((size_t)56 << 20));  // 2 MB

        fused_cr_kernel<<<1024 + 5376, 256, 0, stream>>>(
            x, Wr, Wg, Wu, Wd, Wc, Wg_t, Wu_t, Wd_t, Wc_t,
            d_out, flag, counts, tok_list, wt_list);
        expert3_kernel<<<dim3(E_NUM, T_TOK / 32), 1024, 0, stream>>>(
            x, Wg_t, Wu_t, Wd_t, flag, counts, tok_list, wt_list, ybuf);
        wc3_kernel<<<dim3(T_TOK / 32, 4), 1024, 0, stream>>>(ybuf, Wc_t, d_out, flag);
    } else {
        float* z_bf16 = (float*)(ws + (1u << 20));
        float* z_fp32 = (float*)d_out;
        zero_kernel<<<T_TOK, 256, 0, stream>>>(z_fp32, z_bf16, flag, counts);
        router_kernel<<<T_TOK, 64, 0, stream>>>(x, Wr, d_out, flag, counts, tok_list, wt_list);
        expert_kernel<<<dim3(E_NUM, T_TOK / TT), 256, 0, stream>>>(
            x, Wg, Wu, Wd, flag, counts, tok_list, wt_list, z_fp32, z_bf16);
        wc_kernel<<<T_TOK / WT, 256, 0, stream>>>(z_fp32, z_bf16, Wc, d_out, flag);
    }
}